// Round 14
// baseline (94.601 us; speedup 1.0000x reference)
//
#include <hip/hip_runtime.h>
#include <math.h>

#define BB 8
#define DD 192
#define LLD 128
#define LLP 1024
#define FC1 1024
#define FC2 1024
#define FC3 512
#define NCLS 2
#define LT 8   // l-tile for tiled GEMM kernels

__device__ __forceinline__ void atomicMaxFloat(float* addr, float value) {
    if (value >= 0.f)
        atomicMax((int*)addr, __float_as_int(value));
    else
        atomicMin((unsigned int*)addr, __float_as_uint(value));
}

// ---------------------------------------------------------------------------
// Fused projections: y[b*L+l, e] = sum_d x[b,d,l]*W[e,d] + bias[e]  (f32)
// blocks 0..127 = drug (L=128), 128..1151 = protein (L=1024). 192 threads.
// ---------------------------------------------------------------------------
__global__ void proj_both_kernel(const float* __restrict__ drug,
                                 const float* __restrict__ prot,
                                 const float* __restrict__ Wd,
                                 const float* __restrict__ bdv,
                                 const float* __restrict__ Wp,
                                 const float* __restrict__ bpv,
                                 float* __restrict__ d_att,
                                 float* __restrict__ p_att) {
    int blk = blockIdx.x;
    const float *x, *W, *bias;
    float* y;
    int L, b, l0;
    if (blk < BB * (LLD / LT)) {            // 128 drug tiles
        x = drug; W = Wd; bias = bdv; y = d_att; L = LLD;
        b = blk >> 4; l0 = (blk & 15) * LT;
    } else {                                 // 1024 protein tiles
        int idx = blk - BB * (LLD / LT);
        x = prot; W = Wp; bias = bpv; y = p_att; L = LLP;
        b = idx >> 7; l0 = (idx & 127) * LT;
    }
    int tid = threadIdx.x;  // 0..191

    __shared__ float xs[LT][DD + 4];

    const float* xbase = x + (size_t)b * DD * L + l0;
#pragma unroll
    for (int k = 0; k < LT; ++k) {
        int idx = tid + k * DD;        // covers DD*LT = 1536
        int d = idx >> 3;
        int j = idx & (LT - 1);
        xs[j][d] = xbase[(size_t)d * L + j];
    }
    __syncthreads();

    const int e = tid;
    const float be = bias[e];
    float acc[LT];
#pragma unroll
    for (int j = 0; j < LT; ++j) acc[j] = be;

    const float4* Wr4 = (const float4*)(W + (size_t)e * DD);
#pragma unroll 2
    for (int d4 = 0; d4 < DD / 4; ++d4) {
        float4 w = Wr4[d4];
#pragma unroll
        for (int j = 0; j < LT; ++j) {
            float4 h = *(const float4*)&xs[j][d4 * 4];   // broadcast
            acc[j] = fmaf(h.x, w.x, acc[j]);
            acc[j] = fmaf(h.y, w.y, acc[j]);
            acc[j] = fmaf(h.z, w.z, acc[j]);
            acc[j] = fmaf(h.w, w.w, acc[j]);
        }
    }

    float* ybase = y + ((size_t)b * L + l0) * DD;
#pragma unroll
    for (int j = 0; j < LT; ++j)
        ybase[(size_t)j * DD + e] = acc[j];
}

// ---------------------------------------------------------------------------
// Sort+prefix cross pass, wave-level. One block per (b, d-pair): 768 blocks,
// 256 threads = 4 waves. Waves 0/1: in-register bitonic sort (2 elems/lane)
// + wave suffix scan of one 128-array each; waves 2/3 zero bins + init pair.
// Only 2 __syncthreads in the whole kernel.
// ---------------------------------------------------------------------------
__global__ void cross_sort_kernel(const float* __restrict__ da,
                                  const float* __restrict__ pa,
                                  float* __restrict__ Hd_t,
                                  float* __restrict__ Hp_t,
                                  float* __restrict__ pair) {
    int blk = blockIdx.x;            // 0..767
    int b = blk / (DD / 2);
    int dp = blk - b * (DD / 2);
    int d0 = dp * 2;
    int tid = threadIdx.x;           // 0..255
    int wave = tid >> 6, lane = tid & 63;

    __shared__ float skey[2][LLD];
    __shared__ float sufs[2][LLD + 1];
    __shared__ int   cnt[2][LLD + 1];
    __shared__ float val[2][LLD + 1];

    float s0 = 0.f, s1 = 0.f;
    int i0 = 0, i1 = 0;

    if (wave < 2) {
        const int a = wave;
        const float* base = da + (size_t)b * LLD * DD + d0 + a;
        s0 = base[(size_t)lane * DD];
        s1 = base[(size_t)(lane + 64) * DD];
        i0 = lane; i1 = lane + 64;

        // in-register bitonic ascending sort of 128 elements (2/lane)
        for (int k = 2; k <= LLD; k <<= 1) {
            for (int j = k >> 1; j > 0; j >>= 1) {
                if (j == 64) {
                    if (s0 > s1) {
                        float tk = s0; s0 = s1; s1 = tk;
                        int ti = i0; i0 = i1; i1 = ti;
                    }
                } else {
                    {   // element e = lane
                        float pk = __shfl_xor(s0, j);
                        int   pi = __shfl_xor(i0, j);
                        bool keep_min = (((lane & k) == 0) == ((lane & j) == 0));
                        bool take = keep_min ? (pk < s0) : (pk > s0);
                        if (take) { s0 = pk; i0 = pi; }
                    }
                    {   // element e = lane | 64
                        int e = lane | 64;
                        float pk = __shfl_xor(s1, j);
                        int   pi = __shfl_xor(i1, j);
                        bool keep_min = (((e & k) == 0) == ((e & j) == 0));
                        bool take = keep_min ? (pk < s1) : (pk > s1);
                        if (take) { s1 = pk; i1 = pi; }
                    }
                }
            }
        }

        // wave suffix scans: t1[lane] = sum_{m>=lane} s1[m]; same for s0
        float t1 = s1;
#pragma unroll
        for (int off = 1; off < 64; off <<= 1) {
            int src = lane + off;
            float v = __shfl(t1, src & 63);
            t1 += (src < 64) ? v : 0.f;
        }
        float tot1 = __shfl(t1, 0);
        float t0 = s0;
#pragma unroll
        for (int off = 1; off < 64; off <<= 1) {
            int src = lane + off;
            float v = __shfl(t0, src & 63);
            t0 += (src < 64) ? v : 0.f;
        }

        skey[a][lane] = s0;
        skey[a][lane + 64] = s1;
        sufs[a][lane] = t0 + tot1;
        sufs[a][lane + 64] = t1;
        if (lane == 0) sufs[a][LLD] = 0.f;
    } else if (wave == 2) {
        for (int i = lane; i < 2 * (LLD + 1); i += 64) ((int*)cnt)[i] = 0;
        if (lane < 4) {
            int side = lane >> 1;
            pair[b * 2 * DD + side * DD + d0 + (lane & 1)] = -INFINITY;
        }
    } else {
        for (int i = lane; i < 2 * (LLD + 1); i += 64) ((float*)val)[i] = 0.f;
    }
    __syncthreads();

    // queries: 8 batches of (128 p x 2 d), all 256 threads
    {
        int d_i = tid & 1, prow = tid >> 1;
        float* hprow = Hp_t + ((size_t)b * DD + d0 + d_i) * LLP;
        const float* qbase = pa + (size_t)b * LLP * DD + d0 + d_i;
#pragma unroll
        for (int batch = 0; batch < LLP / 128; ++batch) {
            int p = batch * 128 + prow;
            float q = qbase[(size_t)p * DD];
            float nq = -q;
            int pos = 0;
#pragma unroll
            for (int st = LLD; st > 0; st >>= 1) {
                int np = pos + st;
                if (np <= LLD && skey[d_i][np - 1] <= nq) pos = np;
            }
            hprow[p] = ((float)(LLD - pos) * q + sufs[d_i][pos]) * (1.0f / LLD);
            atomicAdd(&cnt[d_i][pos], 1);
            atomicAdd(&val[d_i][pos], q);
        }
    }
    __syncthreads();

    // histogram prefix (in-register wave scan) + Hd finalize, waves 0/1
    if (wave < 2) {
        const int a = wave;
        int   c0 = cnt[a][lane], c1 = cnt[a][lane + 64];
        float v0 = val[a][lane], v1 = val[a][lane + 64];
#pragma unroll
        for (int off = 1; off < 64; off <<= 1) {
            int src = lane - off;
            int   cu = __shfl(c0, src & 63);
            float vu = __shfl(v0, src & 63);
            if (src >= 0) { c0 += cu; v0 += vu; }
        }
        int   ct0 = __shfl(c0, 63);
        float vt0 = __shfl(v0, 63);
#pragma unroll
        for (int off = 1; off < 64; off <<= 1) {
            int src = lane - off;
            int   cu = __shfl(c1, src & 63);
            float vu = __shfl(v1, src & 63);
            if (src >= 0) { c1 += cu; v1 += vu; }
        }
        c1 += ct0; v1 += vt0;

        float* hdrow = Hd_t + ((size_t)b * DD + d0 + a) * LLD;
        hdrow[i0] = (s0 * (float)c0 + v0) * (1.0f / LLP);
        hdrow[i1] = (s1 * (float)c1 + v1) * (1.0f / LLP);
    }
}

// ---------------------------------------------------------------------------
// Fused sigmoid-GEMM + gated max-pool. Thread = e. Gate stays in registers.
// blocks 0..127 drug -> pair[b, e]; 128..1151 protein -> pair[b, D+e].
// ---------------------------------------------------------------------------
__global__ void gemm_sig_pool_kernel(const float* __restrict__ Hd_t,
                                     const float* __restrict__ Hp_t,
                                     const float* __restrict__ Wa,
                                     const float* __restrict__ ba,
                                     const float* __restrict__ drug,
                                     const float* __restrict__ prot,
                                     float* __restrict__ pair) {
    int blk = blockIdx.x;
    const float* Ht;
    const float* xsrc;
    int L, b, l0, side;
    if (blk < BB * (LLD / LT)) {
        b = blk >> 4; l0 = (blk & 15) * LT;
        Ht = Hd_t; xsrc = drug; L = LLD; side = 0;
    } else {
        int idx = blk - BB * (LLD / LT);
        b = idx >> 7; l0 = (idx & 127) * LT;
        Ht = Hp_t; xsrc = prot; L = LLP; side = 1;
    }
    int tid = threadIdx.x;

    __shared__ float hs[LT][DD + 4];

    const float* hrow = Ht + ((size_t)b * DD + tid) * L + l0;
#pragma unroll
    for (int j = 0; j < LT; ++j) hs[j][tid] = hrow[j];
    __syncthreads();

    const int e = tid;
    const float bias = ba[e];
    float acc[LT];
#pragma unroll
    for (int j = 0; j < LT; ++j) acc[j] = bias;

    const float4* Wr4 = (const float4*)(Wa + (size_t)e * DD);
#pragma unroll 2
    for (int d4 = 0; d4 < DD / 4; ++d4) {
        float4 w = Wr4[d4];
#pragma unroll
        for (int j = 0; j < LT; ++j) {
            float4 h = *(const float4*)&hs[j][d4 * 4];   // broadcast
            acc[j] = fmaf(h.x, w.x, acc[j]);
            acc[j] = fmaf(h.y, w.y, acc[j]);
            acc[j] = fmaf(h.z, w.z, acc[j]);
            acc[j] = fmaf(h.w, w.w, acc[j]);
        }
    }

    const float* xrow = xsrc + ((size_t)b * DD + e) * L + l0;
    float4 x0 = *(const float4*)&xrow[0];
    float4 x1 = *(const float4*)&xrow[4];
    float xv[LT] = {x0.x, x0.y, x0.z, x0.w, x1.x, x1.y, x1.z, x1.w};
    float m = -INFINITY;
#pragma unroll
    for (int j = 0; j < LT; ++j) {
        float gate = 0.5f + 1.0f / (1.0f + __expf(-acc[j]));
        m = fmaxf(m, xv[j] * gate);
    }
    atomicMaxFloat(&pair[b * 2 * DD + side * DD + e], m);
}

// One 64-lane wave per output (b,j). float4 lanes split K (coalesced).
__global__ void fc_wave_kernel(const float* __restrict__ x,
                               const float* __restrict__ W,
                               const float* __restrict__ bias,
                               float* __restrict__ y,
                               int K, int N, int leaky) {
    int gtid = blockIdx.x * blockDim.x + threadIdx.x;
    int wid = gtid >> 6;
    int lane = gtid & 63;
    if (wid >= BB * N) return;
    int b = wid / N;
    int j = wid - b * N;
    const float4* xr = (const float4*)(x + (size_t)b * K);
    const float4* Wr = (const float4*)(W + (size_t)j * K);
    int K4 = K >> 2;
    float s = 0.f;
    for (int k = lane; k < K4; k += 64) {
        float4 xv = xr[k];
        float4 wv = Wr[k];
        s = fmaf(xv.x, wv.x, s);
        s = fmaf(xv.y, wv.y, s);
        s = fmaf(xv.z, wv.z, s);
        s = fmaf(xv.w, wv.w, s);
    }
#pragma unroll
    for (int off = 32; off > 0; off >>= 1) s += __shfl_xor(s, off);
    if (lane == 0) {
        float acc = s + bias[j];
        if (leaky) acc = (acc > 0.f) ? acc : 0.01f * acc;
        y[wid] = acc;
    }
}

extern "C" void kernel_launch(void* const* d_in, const int* in_sizes, int n_in,
                              void* d_out, int out_size, void* d_ws, size_t ws_size,
                              hipStream_t stream) {
    const float* drug = (const float*)d_in[0];   // (B,D,LD)
    const float* prot = (const float*)d_in[1];   // (B,D,LP)
    const float* Wd = (const float*)d_in[2];
    const float* bd = (const float*)d_in[3];
    const float* Wp = (const float*)d_in[4];
    const float* bp = (const float*)d_in[5];
    const float* Wa = (const float*)d_in[6];
    const float* ba = (const float*)d_in[7];
    const float* W1 = (const float*)d_in[8];
    const float* b1 = (const float*)d_in[9];
    const float* W2 = (const float*)d_in[10];
    const float* b2 = (const float*)d_in[11];
    const float* W3 = (const float*)d_in[12];
    const float* b3 = (const float*)d_in[13];
    const float* Wo = (const float*)d_in[14];
    const float* bo = (const float*)d_in[15];
    float* out = (float*)d_out;

    float* ws = (float*)d_ws;
    const size_t n_datt = (size_t)BB * LLD * DD;   // 196608
    const size_t n_patt = (size_t)BB * LLP * DD;   // 1572864
    float* d_att  = ws;                     // (B*LD, D)
    float* p_att  = d_att + n_datt;         // (B*LP, D)
    float* Hd_t   = p_att + n_patt;         // (B,D,LD)
    float* Hp_t   = Hd_t + n_datt;          // (B,D,LP)
    float* pair   = Hp_t + n_patt;          // B*2D
    float* h1     = pair + (size_t)BB * 2 * DD;
    float* h2     = h1 + (size_t)BB * FC1;
    float* h3     = h2 + (size_t)BB * FC2;
    // total ~3.6M floats (~14 MB)

    // 1) both projections, one launch (thread-per-e, LT=8)
    proj_both_kernel<<<BB * (LLD / LT) + BB * (LLP / LT), DD, 0, stream>>>(
        drug, prot, Wd, bd, Wp, bp, d_att, p_att);

    // 2) wave-level sort+prefix cross pass (exact f32) + pair init
    cross_sort_kernel<<<BB * (DD / 2), 256, 0, stream>>>(d_att, p_att, Hd_t, Hp_t, pair);

    // 3) fused sigmoid-GEMM + gated max-pool -> pair
    gemm_sig_pool_kernel<<<BB * (LLD / LT) + BB * (LLP / LT), DD, 0, stream>>>(
        Hd_t, Hp_t, Wa, ba, drug, prot, pair);

    // 4) MLP — wave per output element
    fc_wave_kernel<<<(BB * FC1 * 64) / 256, 256, 0, stream>>>(pair, W1, b1, h1, 2 * DD, FC1, 1);
    fc_wave_kernel<<<(BB * FC2 * 64) / 256, 256, 0, stream>>>(h1, W2, b2, h2, FC1, FC2, 1);
    fc_wave_kernel<<<(BB * FC3 * 64) / 256, 256, 0, stream>>>(h2, W3, b3, h3, FC2, FC3, 1);
    fc_wave_kernel<<<(BB * NCLS * 64 + 255) / 256, 256, 0, stream>>>(h3, Wo, bo, out, FC3, NCLS, 0);
}